// Round 13
// baseline (221.093 us; speedup 1.0000x reference)
//
#include <hip/hip_runtime.h>
#include <hip/hip_bf16.h>

typedef __attribute__((ext_vector_type(8))) short s16x8;
typedef __attribute__((ext_vector_type(4))) short s16x4;
typedef __attribute__((ext_vector_type(4))) float f32x4;
typedef unsigned short u16;

// ---------------- workspace layout (bytes), total <= 41,943,040 (proven) ----------------
#define WS_FWD    0            // 384 int
#define WS_INV    2048         // 384 int (inverse perm: inv[c] = o)
#define WS_SCALE  4096         // 384 f32
#define WS_OFFS   6144         // 384 f32
#define WS_WHI    8192         // packed w_hi bf16: 4*6*384*32*2 = 589,824 B -> ends 598,016
#define WS_WLO    14680064     // packed w_lo bf16: 9*6*384*32*2 = 1,327,104 B -> ends 16,007,168
#define WS_Y2     16777216     // y2' (b,h,w,192) bf16 SWIZZLED = 12,582,912 B -> ends 29,360,128

static __device__ __forceinline__ u16 f2bf(float f) {
    __hip_bfloat16 h = __float2bfloat16(f);
    return *reinterpret_cast<u16*>(&h);
}
static __device__ __forceinline__ float bf2f(u16 u) {
    __hip_bfloat16 h = *reinterpret_cast<__hip_bfloat16*>(&u);
    return __bfloat162float(h);
}

// async global->LDS, 16B per lane (dest = wave-uniform base + lane*16)
static __device__ __forceinline__ void gl_lds16(const void* g, void* l) {
    __builtin_amdgcn_global_load_lds(
        (const __attribute__((address_space(1))) unsigned int*)g,
        (__attribute__((address_space(3))) unsigned int*)l, 16, 0, 0);
}

// Swizzled y2/A-tile GLOBAL row layout: row = (b*32+h), 6144 u16 per row.
// u16 offset within row for (w, c): w*192 + ((g ^ (w&7))<<3) + (c&7), g = c>>3 (0..23).
// LDS staging uses PADDED rows: 34 w-slots (slot = w+1; slots 0 and 33 are zeroed halo
// pads) -> 6528 u16 = 13,056 B per row; stored region is the linear 12,288 B span at
// +384 B. Row stride and offset are multiples of 128 B -> bank pattern (and the proven
// conflict-free swizzle) unchanged. K-loop A-reads are UNCONDITIONAL (no clamp/cndmask):
// pads return zero, exactly reproducing the halo semantics.

// ---------------- fused setup: pack_lo | pack_hi | prep (block-range dispatch) ----------
// Thread per (n, channel-PAIR) for the packs -> u32 writes (no 2B scattered stores).
// blocks [0,144): pack w_lo; [144,288): pack w_hi; [288,864): prep (thread per element).
__global__ __launch_bounds__(256)
void k_setup(const float* __restrict__ pw, const float* __restrict__ an,
             const float* __restrict__ ao, const float* __restrict__ w_hi,
             const float* __restrict__ w_lo, int* __restrict__ fwd,
             int* __restrict__ inv, float* __restrict__ scale,
             float* __restrict__ offs, u16* __restrict__ whi,
             u16* __restrict__ wlo)
{
    const int blk = blockIdx.x;
    const int tid = threadIdx.x;
    if (blk < 144) {
        int gid = blk * 256 + tid;              // 36,864 = 384 n * 96 pairs
        int n = gid / 96;
        int cp = gid - n * 96;
        int kc = cp >> 4, j = cp & 15;
        int c = kc * 32 + 2 * j;
        const float* src = w_lo + ((size_t)n * 192 + c) * 9;   // c and c+1 rows adjacent
#pragma unroll
        for (int t = 0; t < 9; ++t) {
            unsigned pk = (unsigned)f2bf(src[t]) | ((unsigned)f2bf(src[9 + t]) << 16);
            *(unsigned*)&wlo[((size_t)(t * 6 + kc) * 384 + n) * 32 + 2 * j] = pk;
        }
    } else if (blk < 288) {
        int gid = (blk - 144) * 256 + tid;      // 36,864
        int n = gid / 96;
        int cp = gid - n * 96;
        int kc = cp >> 4, j = cp & 15;
        int c = kc * 32 + 2 * j;                // even; c and c+1 share cin, dy
        int cin = c >> 2, dy = (c >> 1) & 1;
        const float* src = w_hi + ((size_t)n * 48 + cin) * 9;
#pragma unroll
        for (int t = 0; t < 4; ++t) {
            int th = t >> 1, tw = t & 1;
            float wv0 = 0.f, wv1 = 0.f;
            if (!(th == 0 && dy == 0)) {
                int ky = (th == 0) ? 0 : 1 + dy;
                if (tw != 0) {                  // dx=0: kx=1; dx=1: kx=2
                    wv0 = src[ky * 3 + 1];
                    wv1 = src[ky * 3 + 2];
                } else {
                    // tw==0: dx=0 masked; dx=1 allowed with kx=0
                    wv1 = src[ky * 3 + 0];
                }
            }
            unsigned pk = (unsigned)f2bf(wv0) | ((unsigned)f2bf(wv1) << 16);
            *(unsigned*)&whi[((size_t)(t * 6 + kc) * 384 + n) * 32 + 2 * j] = pk;
        }
    } else {
        int gid = (blk - 288) * 256 + tid;      // 147,456 exact
        int o = gid / 384;
        int c = gid - o * 384;
        if (pw[gid] > 0.5f) { fwd[o] = c; inv[c] = o; }
        if (gid < 384) {
            scale[gid] = 0.2f * log1pf(expf(0.5f * an[gid]));
            offs[gid]  = ao[gid];
        }
    }
}

// ---------------- fused MFMA gemm + affine + permuted-output epilogue ----------------
// R9-proven schedule (256 thr / 4 waves, 0 bank conflicts) with PADDED-LDS halo:
// A-rows staged as 34 slots (zeroed +-1 pads) -> K-loop A-reads are unconditional
// swizzled ds_read_b128 (no clamp / compare / 4-reg cndmask per fragment — that chain
// was ~150 VALU ops per t-iteration, serial with the MFMA feed; VALUBusy 30% > MfmaUtil).
// T=4: A-tile = down(x1) computed on the fly during staging (k_xd fused), rows h0-1..h0+1.
// T=9: A-tile rows h0-1..h0+2 staged from swizzled y2' via global_load_lds bursts.
// B register-direct from packed weights (L2-resident).
// Epilogue: a_lds channel-major [384][68] reusing staging buffer; coalesced
// affine + permuted out stores; T=4 re-emits y2' in swizzled global layout.
template <int T>
__global__ __launch_bounds__(256)
void f_gemm(const u16* __restrict__ in_t, const u16* __restrict__ wpk,
            const float* __restrict__ bias, const float* __restrict__ x,
            const int* __restrict__ inv, const float* __restrict__ scale,
            const float* __restrict__ offs, u16* __restrict__ y2out,
            float* __restrict__ out)
{
    const int tid = threadIdx.x;
    const int lane = tid & 63;
    const int wave = tid >> 6;
    const int l16 = lane & 15;
    const int quad = lane >> 4;
    const int mblk = blockIdx.x;           // 512 blocks
    const int b = mblk >> 4;
    const int h0 = (mblk & 15) << 1;
    const int n0 = wave * 96;
    const int NR = (T == 4) ? 3 : 4;       // T=4 never reads row 3 (dh in {-1,0})

    __shared__ u16 sm[26112];              // 52,224 B; A-stage (padded rows); reused as a_lds

    // ---- zero the halo pad strips (u32 idx: row r -> [r*3264, +96) and [r*3264+3168, +96)) ----
    for (int z = tid; z < NR * 192; z += 256) {
        int r = z / 192, p = z - (z / 192) * 192;
        ((unsigned*)sm)[r * 3264 + (p < 96 ? p : p + 3072)] = 0u;
    }

    if (T == 4) {
        // ---- stage A = down(x1) computed on the fly (fused k_xd), rows h0-1..h0+1 ----
        for (int r = 0; r < 3; ++r) {
            int ih = h0 - 1 + r;
            if (ih >= 0 && ih < 32) {
#pragma unroll
                for (int it = 0; it < 6; ++it) {
                    int k = it * 256 + tid;     // 1536 chunks: cin=k>>5, dy=(k>>4)&1, q=k&15
                    int cin = k >> 5;
                    int dy = (k >> 4) & 1;
                    int q = k & 15;
                    f32x4 v = *(const f32x4*)&x[((size_t)(b * 96 + cin) * 64
                                                 + (2 * ih + dy)) * 64 + q * 4];
                    int ce = cin * 4 + dy * 2;  // even channel of the pair
                    int g = ce >> 3;
                    int w0 = 2 * q, w1 = w0 + 1;
                    unsigned p0 = (unsigned)f2bf(v[0]) | ((unsigned)f2bf(v[1]) << 16);
                    unsigned p1 = (unsigned)f2bf(v[2]) | ((unsigned)f2bf(v[3]) << 16);
                    *(unsigned*)&sm[r * 6528 + 192 + w0 * 192
                                    + ((g ^ (w0 & 7)) << 3) + (ce & 7)] = p0;
                    *(unsigned*)&sm[r * 6528 + 192 + w1 * 192
                                    + ((g ^ (w1 & 7)) << 3) + (ce & 7)] = p1;
                }
            } else {
                unsigned* ldst = (unsigned*)&sm[r * 6528 + 192];
#pragma unroll
                for (int z = 0; z < 12; ++z)
                    ldst[z * 256 + tid] = 0u;
            }
        }
    } else {
        // ---- stage A-tile rows h0-1 .. h0+2 from swizzled y2' (12,288 B stored span) ----
        for (int r = 0; r < 4; ++r) {
            int ih = h0 - 1 + r;
            char* ldst = (char*)sm + r * 13056 + 384;
            if (ih >= 0 && ih < 32) {
                const char* gsrc = (const char*)in_t + ((size_t)b * 32 + ih) * 12288;
#pragma unroll
                for (int j = 0; j < 3; ++j) {
                    int off = j * 4096 + tid * 16;
                    gl_lds16(gsrc + off, ldst + off);
                }
            } else {
#pragma unroll
                for (int z = 0; z < 12; ++z)
                    ((unsigned*)ldst)[z * 256 + tid] = 0u;
            }
        }
    }
    __syncthreads();   // drains vmcnt (global_load_lds) + lgkmcnt (ds writes)

    const f32x4 zero4 = {0.f, 0.f, 0.f, 0.f};
    f32x4 acc[4][6];
#pragma unroll
    for (int a = 0; a < 4; ++a)
#pragma unroll
        for (int c = 0; c < 6; ++c) acc[a][c] = zero4;

    for (int t = 0; t < T; ++t) {
        const int dh = (T == 4) ? ((t >> 1) - 1) : (t / 3 - 1);
        const int dw = (T == 4) ? ((t & 1) - 1) : (t % 3 - 1);
#pragma unroll
        for (int kc = 0; kc < 6; ++kc) {
            // ---- B fragments: coalesced vector loads from packed weights (L2) ----
            const u16* wp = wpk + ((size_t)(t * 6 + kc) * 384) * 32;
            s16x8 bf[6];
#pragma unroll
            for (int ns = 0; ns < 6; ++ns)
                bf[ns] = *(const s16x8*)(wp + (n0 + ns * 16 + l16) * 32 + quad * 8);
            // ---- A fragments: UNCONDITIONAL swizzled LDS reads (pads supply halo zeros) ----
            const int g = kc * 4 + quad;
            s16x8 af[4];
#pragma unroll
            for (int ms = 0; ms < 4; ++ms) {
                int m = ms * 16 + l16;
                int r = (m >> 5) + dh + 1;                  // 0..NR-1 structurally
                int iw = (m & 31) + dw;                     // -1..32; slot = iw+1
                af[ms] = *(const s16x8*)&sm[r * 6528 + (iw + 1) * 192
                                            + ((g ^ (iw & 7)) << 3)];
            }
            // ---- MFMA ----
#pragma unroll
            for (int ms = 0; ms < 4; ++ms)
#pragma unroll
                for (int ns = 0; ns < 6; ++ns)
                    acc[ms][ns] = __builtin_amdgcn_mfma_f32_16x16x32_bf16(
                        af[ms], bf[ns], acc[ms][ns], 0, 0, 0);
        }
    }

    __syncthreads();   // A-stage region is now dead; reuse sm as a_lds[384][68]

    // ---- epilogue phase 1: a = f2bf(acc + bias) -> a_lds[channel][pixel] ----
    // C/D belief: col(N)=lane&15, row(M)=quad*4+reg; 4 consecutive m -> b64 write
#pragma unroll
    for (int ms = 0; ms < 4; ++ms) {
#pragma unroll
        for (int ns = 0; ns < 6; ++ns) {
            int n = n0 + ns * 16 + l16;
            float bv = bias[n];
            s16x4 pk;
#pragma unroll
            for (int r4 = 0; r4 < 4; ++r4)
                pk[r4] = (short)f2bf(acc[ms][ns][r4] + bv);
            *(s16x4*)&sm[n * 68 + ms * 16 + quad * 4] = pk;
        }
    }
    __syncthreads();

    // ---- epilogue phase A: affine + coalesced permuted out-half ----
    // lane = pixel m (2 rows x 32 w); wave owns channels [wave*48, wave*48+48)
    {
        const int m = lane;
        const int h = h0 + (m >> 5);
        const int w = m & 31;
        for (int i = 0; i < 48; ++i) {
            int c = wave * 48 + i;
            float a_s = bf2f(sm[c * 68 + m]);
            float a_o = bf2f(sm[(c + 192) * 68 + m]);
            int cin = (T == 4 ? 48 : 0) + (c >> 2);
            float xv = x[(((size_t)b * 96 + cin) * 64 + (2 * h + ((c >> 1) & 1))) * 64
                         + (2 * w + (c & 1))];
            float e = expf(0.4f * a_s);
            float sj = 2.f - 4.f / (e + 1.f);
            float y = xv * expf(sj) + a_o;
            int cg = (T == 4) ? (192 + c) : c;
            int o = inv[cg];
            if (T == 4) {
                u16 yb = f2bf(y);
                sm[c * 68 + m] = yb;       // stash y2' (row c owned by this wave)
                out[(((size_t)b * 384 + o) * 32 + h) * 32 + w] =
                    bf2f(yb) * scale[cg] + offs[cg];
            } else {
                out[(((size_t)b * 384 + o) * 32 + h) * 32 + w] =
                    y * scale[cg] + offs[cg];
            }
        }
    }

    // ---- epilogue phase B (T=4 only): emit y2' in SWIZZLED global layout ----
    if (T == 4) {
        __syncthreads();
        for (int it = 0; it < 6; ++it) {
            int v = it * 256 + tid;        // 1536 = 64 pixels x 24 c-octets
            int m2 = v / 24;
            int c8 = v - m2 * 24;          // granule g = c8
            int c0 = c8 * 8;
            int h2 = h0 + (m2 >> 5);
            int w2 = m2 & 31;
            s16x8 yv;
#pragma unroll
            for (int j = 0; j < 8; ++j)
                yv[j] = (short)sm[(c0 + j) * 68 + m2];
            size_t off = ((size_t)b * 32 + h2) * 6144 + w2 * 192 + ((c8 ^ (w2 & 7)) << 3);
            *(s16x8*)&y2out[off] = yv;
        }
    }
}

extern "C" void kernel_launch(void* const* d_in, const int* in_sizes, int n_in,
                              void* d_out, int out_size, void* d_ws, size_t ws_size,
                              hipStream_t stream)
{
    const float* x        = (const float*)d_in[0];
    const float* w_hi     = (const float*)d_in[1];
    const float* b_hi     = (const float*)d_in[2];
    const float* w_lo     = (const float*)d_in[3];
    const float* b_lo     = (const float*)d_in[4];
    const float* act_norm = (const float*)d_in[5];
    const float* act_off  = (const float*)d_in[6];
    const float* perm_w   = (const float*)d_in[7];
    float* out = (float*)d_out;
    char* ws = (char*)d_ws;

    int*   fwd   = (int*)(ws + WS_FWD);
    int*   inv   = (int*)(ws + WS_INV);
    float* scale = (float*)(ws + WS_SCALE);
    float* offs  = (float*)(ws + WS_OFFS);
    u16*   whi   = (u16*)(ws + WS_WHI);
    u16*   wlo   = (u16*)(ws + WS_WLO);
    u16*   y2    = (u16*)(ws + WS_Y2);

    k_setup<<<864, 256, 0, stream>>>(perm_w, act_norm, act_off, w_hi, w_lo,
                                     fwd, inv, scale, offs, whi, wlo);
    f_gemm<4><<<512, 256, 0, stream>>>(y2, whi, b_hi, x, inv, scale, offs, y2, out);
    f_gemm<9><<<512, 256, 0, stream>>>(y2, wlo, b_lo, x, inv, scale, offs, y2, out);
}

// Round 14
// 205.184 us; speedup vs baseline: 1.0775x; 1.0775x over previous
//
#include <hip/hip_runtime.h>
#include <hip/hip_bf16.h>

typedef __attribute__((ext_vector_type(8))) short s16x8;
typedef __attribute__((ext_vector_type(4))) short s16x4;
typedef __attribute__((ext_vector_type(4))) float f32x4;
typedef unsigned short u16;

// ---------------- workspace layout (bytes), total <= 41,943,040 (proven) ----------------
#define WS_FWD    0            // 384 int
#define WS_INV    2048         // 384 int (inverse perm: inv[c] = o)
#define WS_SCALE  4096         // 384 f32
#define WS_OFFS   6144         // 384 f32
#define WS_WHI    8192         // packed w_hi bf16: 4*6*384*32*2 = 589,824 B -> ends 598,016
#define WS_WLO    14680064     // packed w_lo bf16: 9*6*384*32*2 = 1,327,104 B -> ends 16,007,168
#define WS_Y2     16777216     // y2' (b,h,w,192) bf16 SWIZZLED = 12,582,912 B -> ends 29,360,128

static __device__ __forceinline__ u16 f2bf(float f) {
    __hip_bfloat16 h = __float2bfloat16(f);
    return *reinterpret_cast<u16*>(&h);
}
static __device__ __forceinline__ float bf2f(u16 u) {
    __hip_bfloat16 h = *reinterpret_cast<__hip_bfloat16*>(&u);
    return __bfloat162float(h);
}

// async global->LDS, 16B per lane (dest = wave-uniform base + lane*16)
static __device__ __forceinline__ void gl_lds16(const void* g, void* l) {
    __builtin_amdgcn_global_load_lds(
        (const __attribute__((address_space(1))) unsigned int*)g,
        (__attribute__((address_space(3))) unsigned int*)l, 16, 0, 0);
}

// Swizzled y2/A-tile row layout: row = (b*32+h), 6144 u16 per row.
// u16 offset within row for (w, c): w*192 + ((g ^ (w&7))<<3) + (c&7), g = c>>3 (0..23).
// Involution stays inside the row; rows remain linear 12,288B blocks for global_load_lds.

// ---------------- fused setup: pack_lo | pack_hi | prep (block-range dispatch) ----------
// Thread per (n, channel-PAIR) for the packs -> u32 writes (no 2B scattered stores).
// blocks [0,144): pack w_lo; [144,288): pack w_hi; [288,864): prep (thread per element).
__global__ __launch_bounds__(256)
void k_setup(const float* __restrict__ pw, const float* __restrict__ an,
             const float* __restrict__ ao, const float* __restrict__ w_hi,
             const float* __restrict__ w_lo, int* __restrict__ fwd,
             int* __restrict__ inv, float* __restrict__ scale,
             float* __restrict__ offs, u16* __restrict__ whi,
             u16* __restrict__ wlo)
{
    const int blk = blockIdx.x;
    const int tid = threadIdx.x;
    if (blk < 144) {
        int gid = blk * 256 + tid;              // 36,864 = 384 n * 96 pairs
        int n = gid / 96;
        int cp = gid - n * 96;
        int kc = cp >> 4, j = cp & 15;
        int c = kc * 32 + 2 * j;
        const float* src = w_lo + ((size_t)n * 192 + c) * 9;   // c and c+1 rows adjacent
#pragma unroll
        for (int t = 0; t < 9; ++t) {
            unsigned pk = (unsigned)f2bf(src[t]) | ((unsigned)f2bf(src[9 + t]) << 16);
            *(unsigned*)&wlo[((size_t)(t * 6 + kc) * 384 + n) * 32 + 2 * j] = pk;
        }
    } else if (blk < 288) {
        int gid = (blk - 144) * 256 + tid;      // 36,864
        int n = gid / 96;
        int cp = gid - n * 96;
        int kc = cp >> 4, j = cp & 15;
        int c = kc * 32 + 2 * j;                // even; c and c+1 share cin, dy
        int cin = c >> 2, dy = (c >> 1) & 1;
        const float* src = w_hi + ((size_t)n * 48 + cin) * 9;
#pragma unroll
        for (int t = 0; t < 4; ++t) {
            int th = t >> 1, tw = t & 1;
            float wv0 = 0.f, wv1 = 0.f;
            if (!(th == 0 && dy == 0)) {
                int ky = (th == 0) ? 0 : 1 + dy;
                if (tw != 0) {                  // dx=0: kx=1; dx=1: kx=2
                    wv0 = src[ky * 3 + 1];
                    wv1 = src[ky * 3 + 2];
                } else {
                    // tw==0: dx=0 masked; dx=1 allowed with kx=0
                    wv1 = src[ky * 3 + 0];
                }
            }
            unsigned pk = (unsigned)f2bf(wv0) | ((unsigned)f2bf(wv1) << 16);
            *(unsigned*)&whi[((size_t)(t * 6 + kc) * 384 + n) * 32 + 2 * j] = pk;
        }
    } else {
        int gid = (blk - 288) * 256 + tid;      // 147,456 exact
        int o = gid / 384;
        int c = gid - o * 384;
        if (pw[gid] > 0.5f) { fwd[o] = c; inv[c] = o; }
        if (gid < 384) {
            scale[gid] = 0.2f * log1pf(expf(0.5f * an[gid]));
            offs[gid]  = ao[gid];
        }
    }
}

// ---------------- fused MFMA gemm + affine + permuted-output epilogue ----------------
// EXACT R12-proven body (best verified: 204 us total). 256 thr / 4 waves, VGPR ~100,
// 0 bank conflicts. R13's padded-LDS halo regressed (VGPR 152, 2.3M conflicts, spills)
// and is reverted; cndmask halo handling retained.
// T=4: A-tile = down(x1) computed on the fly during staging (k_xd fused), rows h0-1..h0+1
//      (dh in {-1,0} -> row 3 never read; dw<=0 -> no upper iw clamp).
// T=9: A-tile rows h0-1..h0+2 staged from swizzled y2' via global_load_lds bursts.
// K-loop reads A from LDS (XOR-swizzled, conflict-free); B register-direct (L2).
// Epilogue: a_lds channel-major [384][68] reusing staging buffer; coalesced
// affine + permuted out stores; T=4 re-emits y2' in swizzled global layout.
template <int T>
__global__ __launch_bounds__(256)
void f_gemm(const u16* __restrict__ in_t, const u16* __restrict__ wpk,
            const float* __restrict__ bias, const float* __restrict__ x,
            const int* __restrict__ inv, const float* __restrict__ scale,
            const float* __restrict__ offs, u16* __restrict__ y2out,
            float* __restrict__ out)
{
    const int tid = threadIdx.x;
    const int lane = tid & 63;
    const int wave = tid >> 6;
    const int l16 = lane & 15;
    const int quad = lane >> 4;
    const int mblk = blockIdx.x;           // 512 blocks
    const int b = mblk >> 4;
    const int h0 = (mblk & 15) << 1;
    const int n0 = wave * 96;

    __shared__ u16 sm[384 * 68];           // 52,224 B; [0,24576) u16 = A-stage; reused as a_lds

    const s16x8 zero8 = {0, 0, 0, 0, 0, 0, 0, 0};

    if (T == 4) {
        // ---- stage A = down(x1) computed on the fly (fused k_xd), rows h0-1..h0+1 ----
        for (int r = 0; r < 3; ++r) {
            int ih = h0 - 1 + r;
            if (ih >= 0 && ih < 32) {
#pragma unroll
                for (int it = 0; it < 6; ++it) {
                    int k = it * 256 + tid;     // 1536 chunks: cin=k>>5, dy=(k>>4)&1, q=k&15
                    int cin = k >> 5;
                    int dy = (k >> 4) & 1;
                    int q = k & 15;
                    f32x4 v = *(const f32x4*)&x[((size_t)(b * 96 + cin) * 64
                                                 + (2 * ih + dy)) * 64 + q * 4];
                    int ce = cin * 4 + dy * 2;  // even channel of the pair
                    int g = ce >> 3;
                    int w0 = 2 * q, w1 = w0 + 1;
                    unsigned p0 = (unsigned)f2bf(v[0]) | ((unsigned)f2bf(v[1]) << 16);
                    unsigned p1 = (unsigned)f2bf(v[2]) | ((unsigned)f2bf(v[3]) << 16);
                    *(unsigned*)&sm[r * 6144 + w0 * 192 + ((g ^ (w0 & 7)) << 3) + (ce & 7)] = p0;
                    *(unsigned*)&sm[r * 6144 + w1 * 192 + ((g ^ (w1 & 7)) << 3) + (ce & 7)] = p1;
                }
            } else {
#pragma unroll
                for (int z = 0; z < 12; ++z)
                    ((unsigned*)&sm[r * 6144])[z * 256 + tid] = 0u;
            }
        }
    } else {
        // ---- stage A-tile rows h0-1 .. h0+2 from swizzled y2' (12,288 B each, linear) ----
        for (int r = 0; r < 4; ++r) {
            int ih = h0 - 1 + r;
            if (ih >= 0 && ih < 32) {
                const char* gsrc = (const char*)in_t + ((size_t)b * 32 + ih) * 12288;
#pragma unroll
                for (int j = 0; j < 3; ++j) {
                    int off = j * 4096 + tid * 16;
                    gl_lds16(gsrc + off, (char*)sm + r * 12288 + off);
                }
            } else {
#pragma unroll
                for (int j = 0; j < 3; ++j)
                    *(s16x8*)((char*)sm + r * 12288 + j * 4096 + tid * 16) = zero8;
            }
        }
    }
    __syncthreads();   // drains vmcnt (global_load_lds) + lgkmcnt (ds writes)

    const f32x4 zero4 = {0.f, 0.f, 0.f, 0.f};
    f32x4 acc[4][6];
#pragma unroll
    for (int a = 0; a < 4; ++a)
#pragma unroll
        for (int c = 0; c < 6; ++c) acc[a][c] = zero4;

    for (int t = 0; t < T; ++t) {
        const int dh = (T == 4) ? ((t >> 1) - 1) : (t / 3 - 1);
        const int dw = (T == 4) ? ((t & 1) - 1) : (t % 3 - 1);
#pragma unroll
        for (int kc = 0; kc < 6; ++kc) {
            // ---- B fragments: coalesced vector loads from packed weights (L2) ----
            const u16* wp = wpk + ((size_t)(t * 6 + kc) * 384) * 32;
            s16x8 bf[6];
#pragma unroll
            for (int ns = 0; ns < 6; ++ns)
                bf[ns] = *(const s16x8*)(wp + (n0 + ns * 16 + l16) * 32 + quad * 8);
            // ---- A fragments: LDS reads (swizzled, conflict-free), halo via cndmask ----
            const int g = kc * 4 + quad;
            s16x8 af[4];
#pragma unroll
            for (int ms = 0; ms < 4; ++ms) {
                int m = ms * 16 + l16;
                int r = (m >> 5) + dh + 1;                  // 0..NR-1 structurally
                int iw = (m & 31) + dw;
                int iwc = (T == 4) ? (iw < 0 ? 0 : iw)      // dw <= 0: no upper clamp
                                   : (iw < 0 ? 0 : (iw > 31 ? 31 : iw));
                s16x8 v = *(const s16x8*)&sm[r * 6144 + iwc * 192 + ((g ^ (iwc & 7)) << 3)];
                if (iw != iwc) v = zero8;
                af[ms] = v;
            }
            // ---- MFMA ----
#pragma unroll
            for (int ms = 0; ms < 4; ++ms)
#pragma unroll
                for (int ns = 0; ns < 6; ++ns)
                    acc[ms][ns] = __builtin_amdgcn_mfma_f32_16x16x32_bf16(
                        af[ms], bf[ns], acc[ms][ns], 0, 0, 0);
        }
    }

    __syncthreads();   // A-stage region is now dead; reuse sm as a_lds[384][68]

    // ---- epilogue phase 1: a = f2bf(acc + bias) -> a_lds[channel][pixel] ----
    // C/D belief: col(N)=lane&15, row(M)=quad*4+reg; 4 consecutive m -> b64 write
#pragma unroll
    for (int ms = 0; ms < 4; ++ms) {
#pragma unroll
        for (int ns = 0; ns < 6; ++ns) {
            int n = n0 + ns * 16 + l16;
            float bv = bias[n];
            s16x4 pk;
#pragma unroll
            for (int r4 = 0; r4 < 4; ++r4)
                pk[r4] = (short)f2bf(acc[ms][ns][r4] + bv);
            *(s16x4*)&sm[n * 68 + ms * 16 + quad * 4] = pk;
        }
    }
    __syncthreads();

    // ---- epilogue phase A: affine + coalesced permuted out-half ----
    // lane = pixel m (2 rows x 32 w); wave owns channels [wave*48, wave*48+48)
    {
        const int m = lane;
        const int h = h0 + (m >> 5);
        const int w = m & 31;
        for (int i = 0; i < 48; ++i) {
            int c = wave * 48 + i;
            float a_s = bf2f(sm[c * 68 + m]);
            float a_o = bf2f(sm[(c + 192) * 68 + m]);
            int cin = (T == 4 ? 48 : 0) + (c >> 2);
            float xv = x[(((size_t)b * 96 + cin) * 64 + (2 * h + ((c >> 1) & 1))) * 64
                         + (2 * w + (c & 1))];
            float e = expf(0.4f * a_s);
            float sj = 2.f - 4.f / (e + 1.f);
            float y = xv * expf(sj) + a_o;
            int cg = (T == 4) ? (192 + c) : c;
            int o = inv[cg];
            if (T == 4) {
                u16 yb = f2bf(y);
                sm[c * 68 + m] = yb;       // stash y2' (row c owned by this wave)
                out[(((size_t)b * 384 + o) * 32 + h) * 32 + w] =
                    bf2f(yb) * scale[cg] + offs[cg];
            } else {
                out[(((size_t)b * 384 + o) * 32 + h) * 32 + w] =
                    y * scale[cg] + offs[cg];
            }
        }
    }

    // ---- epilogue phase B (T=4 only): emit y2' in SWIZZLED global layout ----
    if (T == 4) {
        __syncthreads();
        for (int it = 0; it < 6; ++it) {
            int v = it * 256 + tid;        // 1536 = 64 pixels x 24 c-octets
            int m2 = v / 24;
            int c8 = v - m2 * 24;          // granule g = c8
            int c0 = c8 * 8;
            int h2 = h0 + (m2 >> 5);
            int w2 = m2 & 31;
            s16x8 yv;
#pragma unroll
            for (int j = 0; j < 8; ++j)
                yv[j] = (short)sm[(c0 + j) * 68 + m2];
            size_t off = ((size_t)b * 32 + h2) * 6144 + w2 * 192 + ((c8 ^ (w2 & 7)) << 3);
            *(s16x8*)&y2out[off] = yv;
        }
    }
}

extern "C" void kernel_launch(void* const* d_in, const int* in_sizes, int n_in,
                              void* d_out, int out_size, void* d_ws, size_t ws_size,
                              hipStream_t stream)
{
    const float* x        = (const float*)d_in[0];
    const float* w_hi     = (const float*)d_in[1];
    const float* b_hi     = (const float*)d_in[2];
    const float* w_lo     = (const float*)d_in[3];
    const float* b_lo     = (const float*)d_in[4];
    const float* act_norm = (const float*)d_in[5];
    const float* act_off  = (const float*)d_in[6];
    const float* perm_w   = (const float*)d_in[7];
    float* out = (float*)d_out;
    char* ws = (char*)d_ws;

    int*   fwd   = (int*)(ws + WS_FWD);
    int*   inv   = (int*)(ws + WS_INV);
    float* scale = (float*)(ws + WS_SCALE);
    float* offs  = (float*)(ws + WS_OFFS);
    u16*   whi   = (u16*)(ws + WS_WHI);
    u16*   wlo   = (u16*)(ws + WS_WLO);
    u16*   y2    = (u16*)(ws + WS_Y2);

    k_setup<<<864, 256, 0, stream>>>(perm_w, act_norm, act_off, w_hi, w_lo,
                                     fwd, inv, scale, offs, whi, wlo);
    f_gemm<4><<<512, 256, 0, stream>>>(y2, whi, b_hi, x, inv, scale, offs, y2, out);
    f_gemm<9><<<512, 256, 0, stream>>>(y2, wlo, b_lo, x, inv, scale, offs, y2, out);
}

// Round 15
// 193.440 us; speedup vs baseline: 1.1430x; 1.0607x over previous
//
#include <hip/hip_runtime.h>
#include <hip/hip_bf16.h>

typedef __attribute__((ext_vector_type(8))) short s16x8;
typedef __attribute__((ext_vector_type(4))) short s16x4;
typedef __attribute__((ext_vector_type(4))) float f32x4;
typedef unsigned short u16;

// ---------------- workspace layout (bytes), total <= 41,943,040 (proven) ----------------
#define WS_FWD    0            // 384 int
#define WS_INV    2048         // 384 int (inverse perm: inv[c] = o)
#define WS_SCALE  4096         // 384 f32
#define WS_OFFS   6144         // 384 f32
#define WS_WHI    8192         // packed w_hi bf16: 4*6*384*32*2 = 589,824 B -> ends 598,016
#define WS_WLO    14680064     // packed w_lo bf16: 9*6*384*32*2 = 1,327,104 B -> ends 16,007,168
#define WS_Y2     16777216     // y2' (b,h,w,192) bf16 SWIZZLED = 12,582,912 B -> ends 29,360,128

static __device__ __forceinline__ u16 f2bf(float f) {
    __hip_bfloat16 h = __float2bfloat16(f);
    return *reinterpret_cast<u16*>(&h);
}
static __device__ __forceinline__ float bf2f(u16 u) {
    __hip_bfloat16 h = *reinterpret_cast<__hip_bfloat16*>(&u);
    return __bfloat162float(h);
}

// async global->LDS, 16B per lane (dest = wave-uniform base + lane*16)
static __device__ __forceinline__ void gl_lds16(const void* g, void* l) {
    __builtin_amdgcn_global_load_lds(
        (const __attribute__((address_space(1))) unsigned int*)g,
        (__attribute__((address_space(3))) unsigned int*)l, 16, 0, 0);
}

// Swizzled y2/A-tile row layout: row = (b*32+h), 6144 u16 per row.
// u16 offset within row for (w, c): w*192 + ((g ^ (w&7))<<3) + (c&7), g = c>>3 (0..23).
// Involution stays inside the row; rows remain linear 12,288B blocks for global_load_lds.

// ---------------- fused setup: pack_lo | pack_hi | prep (block-range dispatch) ----------
// Thread per (n, channel-PAIR) for the packs -> u32 writes (no 2B scattered stores).
// blocks [0,144): pack w_lo; [144,288): pack w_hi; [288,864): prep (thread per element).
__global__ __launch_bounds__(256)
void k_setup(const float* __restrict__ pw, const float* __restrict__ an,
             const float* __restrict__ ao, const float* __restrict__ w_hi,
             const float* __restrict__ w_lo, int* __restrict__ fwd,
             int* __restrict__ inv, float* __restrict__ scale,
             float* __restrict__ offs, u16* __restrict__ whi,
             u16* __restrict__ wlo)
{
    const int blk = blockIdx.x;
    const int tid = threadIdx.x;
    if (blk < 144) {
        int gid = blk * 256 + tid;              // 36,864 = 384 n * 96 pairs
        int n = gid / 96;
        int cp = gid - n * 96;
        int kc = cp >> 4, j = cp & 15;
        int c = kc * 32 + 2 * j;
        const float* src = w_lo + ((size_t)n * 192 + c) * 9;   // c and c+1 rows adjacent
#pragma unroll
        for (int t = 0; t < 9; ++t) {
            unsigned pk = (unsigned)f2bf(src[t]) | ((unsigned)f2bf(src[9 + t]) << 16);
            *(unsigned*)&wlo[((size_t)(t * 6 + kc) * 384 + n) * 32 + 2 * j] = pk;
        }
    } else if (blk < 288) {
        int gid = (blk - 144) * 256 + tid;      // 36,864
        int n = gid / 96;
        int cp = gid - n * 96;
        int kc = cp >> 4, j = cp & 15;
        int c = kc * 32 + 2 * j;                // even; c and c+1 share cin, dy
        int cin = c >> 2, dy = (c >> 1) & 1;
        const float* src = w_hi + ((size_t)n * 48 + cin) * 9;
#pragma unroll
        for (int t = 0; t < 4; ++t) {
            int th = t >> 1, tw = t & 1;
            float wv0 = 0.f, wv1 = 0.f;
            if (!(th == 0 && dy == 0)) {
                int ky = (th == 0) ? 0 : 1 + dy;
                if (tw != 0) {                  // dx=0: kx=1; dx=1: kx=2
                    wv0 = src[ky * 3 + 1];
                    wv1 = src[ky * 3 + 2];
                } else {
                    // tw==0: dx=0 masked; dx=1 allowed with kx=0
                    wv1 = src[ky * 3 + 0];
                }
            }
            unsigned pk = (unsigned)f2bf(wv0) | ((unsigned)f2bf(wv1) << 16);
            *(unsigned*)&whi[((size_t)(t * 6 + kc) * 384 + n) * 32 + 2 * j] = pk;
        }
    } else {
        int gid = (blk - 288) * 256 + tid;      // 147,456 exact
        int o = gid / 384;
        int c = gid - o * 384;
        if (pw[gid] > 0.5f) { fwd[o] = c; inv[c] = o; }
        if (gid < 384) {
            scale[gid] = 0.2f * log1pf(expf(0.5f * an[gid]));
            offs[gid]  = ao[gid];
        }
    }
}

// ---------------- fused MFMA gemm + affine + permuted-output epilogue ----------------
// R12-proven body with ONE isolated change: epilogue phase A batched 8-wide with
// hoisted vectorized x-loads (8 channels = 2 cin x 2 rows -> 4 float2 loads + 16 LDS
// reads issued together, then compute/store 8). Tests the "48 serialized scattered
// x-gathers dominate the T-independent 67us" hypothesis. No numeric change.
// T=4: A-tile = down(x1) computed on the fly during staging (k_xd fused), rows h0-1..h0+1.
// T=9: A-tile rows h0-1..h0+2 staged from swizzled y2' via global_load_lds bursts.
// K-loop reads A from LDS (XOR-swizzled, conflict-free); B register-direct (L2).
template <int T>
__global__ __launch_bounds__(256)
void f_gemm(const u16* __restrict__ in_t, const u16* __restrict__ wpk,
            const float* __restrict__ bias, const float* __restrict__ x,
            const int* __restrict__ inv, const float* __restrict__ scale,
            const float* __restrict__ offs, u16* __restrict__ y2out,
            float* __restrict__ out)
{
    const int tid = threadIdx.x;
    const int lane = tid & 63;
    const int wave = tid >> 6;
    const int l16 = lane & 15;
    const int quad = lane >> 4;
    const int mblk = blockIdx.x;           // 512 blocks
    const int b = mblk >> 4;
    const int h0 = (mblk & 15) << 1;
    const int n0 = wave * 96;

    __shared__ u16 sm[384 * 68];           // 52,224 B; [0,24576) u16 = A-stage; reused as a_lds

    const s16x8 zero8 = {0, 0, 0, 0, 0, 0, 0, 0};

    if (T == 4) {
        // ---- stage A = down(x1) computed on the fly (fused k_xd), rows h0-1..h0+1 ----
        for (int r = 0; r < 3; ++r) {
            int ih = h0 - 1 + r;
            if (ih >= 0 && ih < 32) {
#pragma unroll
                for (int it = 0; it < 6; ++it) {
                    int k = it * 256 + tid;     // 1536 chunks: cin=k>>5, dy=(k>>4)&1, q=k&15
                    int cin = k >> 5;
                    int dy = (k >> 4) & 1;
                    int q = k & 15;
                    f32x4 v = *(const f32x4*)&x[((size_t)(b * 96 + cin) * 64
                                                 + (2 * ih + dy)) * 64 + q * 4];
                    int ce = cin * 4 + dy * 2;  // even channel of the pair
                    int g = ce >> 3;
                    int w0 = 2 * q, w1 = w0 + 1;
                    unsigned p0 = (unsigned)f2bf(v[0]) | ((unsigned)f2bf(v[1]) << 16);
                    unsigned p1 = (unsigned)f2bf(v[2]) | ((unsigned)f2bf(v[3]) << 16);
                    *(unsigned*)&sm[r * 6144 + w0 * 192 + ((g ^ (w0 & 7)) << 3) + (ce & 7)] = p0;
                    *(unsigned*)&sm[r * 6144 + w1 * 192 + ((g ^ (w1 & 7)) << 3) + (ce & 7)] = p1;
                }
            } else {
#pragma unroll
                for (int z = 0; z < 12; ++z)
                    ((unsigned*)&sm[r * 6144])[z * 256 + tid] = 0u;
            }
        }
    } else {
        // ---- stage A-tile rows h0-1 .. h0+2 from swizzled y2' (12,288 B each, linear) ----
        for (int r = 0; r < 4; ++r) {
            int ih = h0 - 1 + r;
            if (ih >= 0 && ih < 32) {
                const char* gsrc = (const char*)in_t + ((size_t)b * 32 + ih) * 12288;
#pragma unroll
                for (int j = 0; j < 3; ++j) {
                    int off = j * 4096 + tid * 16;
                    gl_lds16(gsrc + off, (char*)sm + r * 12288 + off);
                }
            } else {
#pragma unroll
                for (int j = 0; j < 3; ++j)
                    *(s16x8*)((char*)sm + r * 12288 + j * 4096 + tid * 16) = zero8;
            }
        }
    }
    __syncthreads();   // drains vmcnt (global_load_lds) + lgkmcnt (ds writes)

    const f32x4 zero4 = {0.f, 0.f, 0.f, 0.f};
    f32x4 acc[4][6];
#pragma unroll
    for (int a = 0; a < 4; ++a)
#pragma unroll
        for (int c = 0; c < 6; ++c) acc[a][c] = zero4;

    for (int t = 0; t < T; ++t) {
        const int dh = (T == 4) ? ((t >> 1) - 1) : (t / 3 - 1);
        const int dw = (T == 4) ? ((t & 1) - 1) : (t % 3 - 1);
#pragma unroll
        for (int kc = 0; kc < 6; ++kc) {
            // ---- B fragments: coalesced vector loads from packed weights (L2) ----
            const u16* wp = wpk + ((size_t)(t * 6 + kc) * 384) * 32;
            s16x8 bf[6];
#pragma unroll
            for (int ns = 0; ns < 6; ++ns)
                bf[ns] = *(const s16x8*)(wp + (n0 + ns * 16 + l16) * 32 + quad * 8);
            // ---- A fragments: LDS reads (swizzled, conflict-free), halo via cndmask ----
            const int g = kc * 4 + quad;
            s16x8 af[4];
#pragma unroll
            for (int ms = 0; ms < 4; ++ms) {
                int m = ms * 16 + l16;
                int r = (m >> 5) + dh + 1;                  // 0..NR-1 structurally
                int iw = (m & 31) + dw;
                int iwc = (T == 4) ? (iw < 0 ? 0 : iw)      // dw <= 0: no upper clamp
                                   : (iw < 0 ? 0 : (iw > 31 ? 31 : iw));
                s16x8 v = *(const s16x8*)&sm[r * 6144 + iwc * 192 + ((g ^ (iwc & 7)) << 3)];
                if (iw != iwc) v = zero8;
                af[ms] = v;
            }
            // ---- MFMA ----
#pragma unroll
            for (int ms = 0; ms < 4; ++ms)
#pragma unroll
                for (int ns = 0; ns < 6; ++ns)
                    acc[ms][ns] = __builtin_amdgcn_mfma_f32_16x16x32_bf16(
                        af[ms], bf[ns], acc[ms][ns], 0, 0, 0);
        }
    }

    __syncthreads();   // A-stage region is now dead; reuse sm as a_lds[384][68]

    // ---- epilogue phase 1: a = f2bf(acc + bias) -> a_lds[channel][pixel] ----
    // C/D belief: col(N)=lane&15, row(M)=quad*4+reg; 4 consecutive m -> b64 write
#pragma unroll
    for (int ms = 0; ms < 4; ++ms) {
#pragma unroll
        for (int ns = 0; ns < 6; ++ns) {
            int n = n0 + ns * 16 + l16;
            float bv = bias[n];
            s16x4 pk;
#pragma unroll
            for (int r4 = 0; r4 < 4; ++r4)
                pk[r4] = (short)f2bf(acc[ms][ns][r4] + bv);
            *(s16x4*)&sm[n * 68 + ms * 16 + quad * 4] = pk;
        }
    }
    __syncthreads();

    // ---- epilogue phase A: 8-wide batched affine + coalesced permuted out-half ----
    // lane = pixel m (2 rows x 32 w); wave owns channels [wave*48, wave*48+48).
    // Per batch of 8 channels (= 2 cin x {dy,dx}): 4 float2 x-loads + 16 LDS reads
    // hoisted together (MLP ~8-12 vs ~2 in the scalar loop), then compute/store 8.
    {
        const int m = lane;
        const int h = h0 + (m >> 5);
        const int w = m & 31;
        const int cbase = wave * 48;
        const float* xb = x + ((size_t)b * 96 + (T == 4 ? 48 : 0)) * 4096
                          + (2 * h) * 64 + 2 * w;   // base at (cin=0 local, row 2h, col 2w)
#pragma unroll
        for (int i0 = 0; i0 < 48; i0 += 8) {
            int cin0 = (cbase + i0) >> 2;           // local cin of j=0..3 (global cin = base+cin0)
            // hoisted x loads: rows 2h (dy=0) and 2h+1 (dy=1) for cin0 and cin0+1
            float2 xa0 = *(const float2*)(xb + (size_t)cin0 * 4096);
            float2 xa1 = *(const float2*)(xb + (size_t)cin0 * 4096 + 64);
            float2 xb0 = *(const float2*)(xb + (size_t)(cin0 + 1) * 4096);
            float2 xb1 = *(const float2*)(xb + (size_t)(cin0 + 1) * 4096 + 64);
            float xs[8] = {xa0.x, xa0.y, xa1.x, xa1.y, xb0.x, xb0.y, xb1.x, xb1.y};
            // hoisted LDS reads
            float as_[8], ao_[8];
#pragma unroll
            for (int j = 0; j < 8; ++j) {
                int c = cbase + i0 + j;
                as_[j] = bf2f(sm[c * 68 + m]);
                ao_[j] = bf2f(sm[(c + 192) * 68 + m]);
            }
            // compute + store (identical numerics/order to the scalar loop)
#pragma unroll
            for (int j = 0; j < 8; ++j) {
                int c = cbase + i0 + j;
                float e = expf(0.4f * as_[j]);
                float sj = 2.f - 4.f / (e + 1.f);
                float y = xs[j] * expf(sj) + ao_[j];
                int cg = (T == 4) ? (192 + c) : c;
                int o = inv[cg];
                if (T == 4) {
                    u16 yb = f2bf(y);
                    sm[c * 68 + m] = yb;   // stash y2' (row c owned by this wave)
                    out[(((size_t)b * 384 + o) * 32 + h) * 32 + w] =
                        bf2f(yb) * scale[cg] + offs[cg];
                } else {
                    out[(((size_t)b * 384 + o) * 32 + h) * 32 + w] =
                        y * scale[cg] + offs[cg];
                }
            }
        }
    }

    // ---- epilogue phase B (T=4 only): emit y2' in SWIZZLED global layout ----
    if (T == 4) {
        __syncthreads();
        for (int it = 0; it < 6; ++it) {
            int v = it * 256 + tid;        // 1536 = 64 pixels x 24 c-octets
            int m2 = v / 24;
            int c8 = v - m2 * 24;          // granule g = c8
            int c0 = c8 * 8;
            int h2 = h0 + (m2 >> 5);
            int w2 = m2 & 31;
            s16x8 yv;
#pragma unroll
            for (int j = 0; j < 8; ++j)
                yv[j] = (short)sm[(c0 + j) * 68 + m2];
            size_t off = ((size_t)b * 32 + h2) * 6144 + w2 * 192 + ((c8 ^ (w2 & 7)) << 3);
            *(s16x8*)&y2out[off] = yv;
        }
    }
}

extern "C" void kernel_launch(void* const* d_in, const int* in_sizes, int n_in,
                              void* d_out, int out_size, void* d_ws, size_t ws_size,
                              hipStream_t stream)
{
    const float* x        = (const float*)d_in[0];
    const float* w_hi     = (const float*)d_in[1];
    const float* b_hi     = (const float*)d_in[2];
    const float* w_lo     = (const float*)d_in[3];
    const float* b_lo     = (const float*)d_in[4];
    const float* act_norm = (const float*)d_in[5];
    const float* act_off  = (const float*)d_in[6];
    const float* perm_w   = (const float*)d_in[7];
    float* out = (float*)d_out;
    char* ws = (char*)d_ws;

    int*   fwd   = (int*)(ws + WS_FWD);
    int*   inv   = (int*)(ws + WS_INV);
    float* scale = (float*)(ws + WS_SCALE);
    float* offs  = (float*)(ws + WS_OFFS);
    u16*   whi   = (u16*)(ws + WS_WHI);
    u16*   wlo   = (u16*)(ws + WS_WLO);
    u16*   y2    = (u16*)(ws + WS_Y2);

    k_setup<<<864, 256, 0, stream>>>(perm_w, act_norm, act_off, w_hi, w_lo,
                                     fwd, inv, scale, offs, whi, wlo);
    f_gemm<4><<<512, 256, 0, stream>>>(y2, whi, b_hi, x, inv, scale, offs, y2, out);
    f_gemm<9><<<512, 256, 0, stream>>>(y2, wlo, b_lo, x, inv, scale, offs, y2, out);
}

// Round 16
// 190.184 us; speedup vs baseline: 1.1625x; 1.0171x over previous
//
#include <hip/hip_runtime.h>
#include <hip/hip_bf16.h>

typedef __attribute__((ext_vector_type(8))) short s16x8;
typedef __attribute__((ext_vector_type(4))) short s16x4;
typedef __attribute__((ext_vector_type(4))) float f32x4;
typedef unsigned short u16;

// ---------------- workspace layout (bytes), total <= 41,943,040 (proven) ----------------
#define WS_FWD    0            // 384 int
#define WS_INV    2048         // 384 int (inverse perm: inv[c] = o)
#define WS_SCALE  4096         // 384 f32
#define WS_OFFS   6144         // 384 f32
#define WS_WHI    8192         // packed w_hi bf16: 4*6*384*32*2 = 589,824 B -> ends 598,016
#define WS_WLO    14680064     // packed w_lo bf16: 9*6*384*32*2 = 1,327,104 B -> ends 16,007,168
#define WS_Y2     16777216     // y2' (b,h,w,192) bf16 SWIZZLED = 12,582,912 B -> ends 29,360,128

static __device__ __forceinline__ u16 f2bf(float f) {
    __hip_bfloat16 h = __float2bfloat16(f);
    return *reinterpret_cast<u16*>(&h);
}
static __device__ __forceinline__ float bf2f(u16 u) {
    __hip_bfloat16 h = *reinterpret_cast<__hip_bfloat16*>(&u);
    return __bfloat162float(h);
}

// fast affine factor: exp(2*tanh(0.2*a)) via hardware v_exp + fast rcp.
// Relative error ~1e-6 on the bounded range (sj in (-2,2)) — two orders below the
// bf16 rounding noise that dominates absmax (0.1875 vs 0.615 threshold).
static __device__ __forceinline__ float aff_fast(float a_s) {
    float e = __expf(0.4f * a_s);
    float sj = 2.f - __fdividef(4.f, e + 1.f);
    return __expf(sj);
}

// async global->LDS, 16B per lane (dest = wave-uniform base + lane*16)
static __device__ __forceinline__ void gl_lds16(const void* g, void* l) {
    __builtin_amdgcn_global_load_lds(
        (const __attribute__((address_space(1))) unsigned int*)g,
        (__attribute__((address_space(3))) unsigned int*)l, 16, 0, 0);
}

// Swizzled y2/A-tile row layout: row = (b*32+h), 6144 u16 per row.
// u16 offset within row for (w, c): w*192 + ((g ^ (w&7))<<3) + (c&7), g = c>>3 (0..23).
// Involution stays inside the row; rows remain linear 12,288B blocks for global_load_lds.

// ---------------- fused setup: pack_lo | pack_hi | prep (block-range dispatch) ----------
// Thread per (n, channel-PAIR) for the packs -> u32 writes (no 2B scattered stores).
// blocks [0,144): pack w_lo; [144,288): pack w_hi; [288,864): prep (thread per element).
__global__ __launch_bounds__(256)
void k_setup(const float* __restrict__ pw, const float* __restrict__ an,
             const float* __restrict__ ao, const float* __restrict__ w_hi,
             const float* __restrict__ w_lo, int* __restrict__ fwd,
             int* __restrict__ inv, float* __restrict__ scale,
             float* __restrict__ offs, u16* __restrict__ whi,
             u16* __restrict__ wlo)
{
    const int blk = blockIdx.x;
    const int tid = threadIdx.x;
    if (blk < 144) {
        int gid = blk * 256 + tid;              // 36,864 = 384 n * 96 pairs
        int n = gid / 96;
        int cp = gid - n * 96;
        int kc = cp >> 4, j = cp & 15;
        int c = kc * 32 + 2 * j;
        const float* src = w_lo + ((size_t)n * 192 + c) * 9;   // c and c+1 rows adjacent
#pragma unroll
        for (int t = 0; t < 9; ++t) {
            unsigned pk = (unsigned)f2bf(src[t]) | ((unsigned)f2bf(src[9 + t]) << 16);
            *(unsigned*)&wlo[((size_t)(t * 6 + kc) * 384 + n) * 32 + 2 * j] = pk;
        }
    } else if (blk < 288) {
        int gid = (blk - 144) * 256 + tid;      // 36,864
        int n = gid / 96;
        int cp = gid - n * 96;
        int kc = cp >> 4, j = cp & 15;
        int c = kc * 32 + 2 * j;                // even; c and c+1 share cin, dy
        int cin = c >> 2, dy = (c >> 1) & 1;
        const float* src = w_hi + ((size_t)n * 48 + cin) * 9;
#pragma unroll
        for (int t = 0; t < 4; ++t) {
            int th = t >> 1, tw = t & 1;
            float wv0 = 0.f, wv1 = 0.f;
            if (!(th == 0 && dy == 0)) {
                int ky = (th == 0) ? 0 : 1 + dy;
                if (tw != 0) {                  // dx=0: kx=1; dx=1: kx=2
                    wv0 = src[ky * 3 + 1];
                    wv1 = src[ky * 3 + 2];
                } else {
                    // tw==0: dx=0 masked; dx=1 allowed with kx=0
                    wv1 = src[ky * 3 + 0];
                }
            }
            unsigned pk = (unsigned)f2bf(wv0) | ((unsigned)f2bf(wv1) << 16);
            *(unsigned*)&whi[((size_t)(t * 6 + kc) * 384 + n) * 32 + 2 * j] = pk;
        }
    } else {
        int gid = (blk - 288) * 256 + tid;      // 147,456 exact
        int o = gid / 384;
        int c = gid - o * 384;
        if (pw[gid] > 0.5f) { fwd[o] = c; inv[c] = o; }
        if (gid < 384) {
            scale[gid] = 0.2f * log1pf(expf(0.5f * an[gid]));
            offs[gid]  = ao[gid];
        }
    }
}

// ---------------- fused MFMA gemm + affine + permuted-output epilogue ----------------
// R15-proven body with ONE isolated change: epilogue affine chain uses hardware-direct
// __expf + __fdividef (libm expf's range handling + IEEE div were ~1100 VALU ops/thread;
// VALUBusy 32% > MfmaUtil 26.5%). No structural change.
// T=4: A-tile = down(x1) computed on the fly during staging (k_xd fused), rows h0-1..h0+1.
// T=9: A-tile rows h0-1..h0+2 staged from swizzled y2' via global_load_lds bursts.
// K-loop reads A from LDS (XOR-swizzled, conflict-free); B register-direct (L2).
// Epilogue phase A: 8-wide batched (4 float2 x-loads + 16 LDS reads hoisted per batch).
template <int T>
__global__ __launch_bounds__(256)
void f_gemm(const u16* __restrict__ in_t, const u16* __restrict__ wpk,
            const float* __restrict__ bias, const float* __restrict__ x,
            const int* __restrict__ inv, const float* __restrict__ scale,
            const float* __restrict__ offs, u16* __restrict__ y2out,
            float* __restrict__ out)
{
    const int tid = threadIdx.x;
    const int lane = tid & 63;
    const int wave = tid >> 6;
    const int l16 = lane & 15;
    const int quad = lane >> 4;
    const int mblk = blockIdx.x;           // 512 blocks
    const int b = mblk >> 4;
    const int h0 = (mblk & 15) << 1;
    const int n0 = wave * 96;

    __shared__ u16 sm[384 * 68];           // 52,224 B; [0,24576) u16 = A-stage; reused as a_lds

    const s16x8 zero8 = {0, 0, 0, 0, 0, 0, 0, 0};

    if (T == 4) {
        // ---- stage A = down(x1) computed on the fly (fused k_xd), rows h0-1..h0+1 ----
        for (int r = 0; r < 3; ++r) {
            int ih = h0 - 1 + r;
            if (ih >= 0 && ih < 32) {
#pragma unroll
                for (int it = 0; it < 6; ++it) {
                    int k = it * 256 + tid;     // 1536 chunks: cin=k>>5, dy=(k>>4)&1, q=k&15
                    int cin = k >> 5;
                    int dy = (k >> 4) & 1;
                    int q = k & 15;
                    f32x4 v = *(const f32x4*)&x[((size_t)(b * 96 + cin) * 64
                                                 + (2 * ih + dy)) * 64 + q * 4];
                    int ce = cin * 4 + dy * 2;  // even channel of the pair
                    int g = ce >> 3;
                    int w0 = 2 * q, w1 = w0 + 1;
                    unsigned p0 = (unsigned)f2bf(v[0]) | ((unsigned)f2bf(v[1]) << 16);
                    unsigned p1 = (unsigned)f2bf(v[2]) | ((unsigned)f2bf(v[3]) << 16);
                    *(unsigned*)&sm[r * 6144 + w0 * 192 + ((g ^ (w0 & 7)) << 3) + (ce & 7)] = p0;
                    *(unsigned*)&sm[r * 6144 + w1 * 192 + ((g ^ (w1 & 7)) << 3) + (ce & 7)] = p1;
                }
            } else {
#pragma unroll
                for (int z = 0; z < 12; ++z)
                    ((unsigned*)&sm[r * 6144])[z * 256 + tid] = 0u;
            }
        }
    } else {
        // ---- stage A-tile rows h0-1 .. h0+2 from swizzled y2' (12,288 B each, linear) ----
        for (int r = 0; r < 4; ++r) {
            int ih = h0 - 1 + r;
            if (ih >= 0 && ih < 32) {
                const char* gsrc = (const char*)in_t + ((size_t)b * 32 + ih) * 12288;
#pragma unroll
                for (int j = 0; j < 3; ++j) {
                    int off = j * 4096 + tid * 16;
                    gl_lds16(gsrc + off, (char*)sm + r * 12288 + off);
                }
            } else {
#pragma unroll
                for (int j = 0; j < 3; ++j)
                    *(s16x8*)((char*)sm + r * 12288 + j * 4096 + tid * 16) = zero8;
            }
        }
    }
    __syncthreads();   // drains vmcnt (global_load_lds) + lgkmcnt (ds writes)

    const f32x4 zero4 = {0.f, 0.f, 0.f, 0.f};
    f32x4 acc[4][6];
#pragma unroll
    for (int a = 0; a < 4; ++a)
#pragma unroll
        for (int c = 0; c < 6; ++c) acc[a][c] = zero4;

    for (int t = 0; t < T; ++t) {
        const int dh = (T == 4) ? ((t >> 1) - 1) : (t / 3 - 1);
        const int dw = (T == 4) ? ((t & 1) - 1) : (t % 3 - 1);
#pragma unroll
        for (int kc = 0; kc < 6; ++kc) {
            // ---- B fragments: coalesced vector loads from packed weights (L2) ----
            const u16* wp = wpk + ((size_t)(t * 6 + kc) * 384) * 32;
            s16x8 bf[6];
#pragma unroll
            for (int ns = 0; ns < 6; ++ns)
                bf[ns] = *(const s16x8*)(wp + (n0 + ns * 16 + l16) * 32 + quad * 8);
            // ---- A fragments: LDS reads (swizzled, conflict-free), halo via cndmask ----
            const int g = kc * 4 + quad;
            s16x8 af[4];
#pragma unroll
            for (int ms = 0; ms < 4; ++ms) {
                int m = ms * 16 + l16;
                int r = (m >> 5) + dh + 1;                  // 0..NR-1 structurally
                int iw = (m & 31) + dw;
                int iwc = (T == 4) ? (iw < 0 ? 0 : iw)      // dw <= 0: no upper clamp
                                   : (iw < 0 ? 0 : (iw > 31 ? 31 : iw));
                s16x8 v = *(const s16x8*)&sm[r * 6144 + iwc * 192 + ((g ^ (iwc & 7)) << 3)];
                if (iw != iwc) v = zero8;
                af[ms] = v;
            }
            // ---- MFMA ----
#pragma unroll
            for (int ms = 0; ms < 4; ++ms)
#pragma unroll
                for (int ns = 0; ns < 6; ++ns)
                    acc[ms][ns] = __builtin_amdgcn_mfma_f32_16x16x32_bf16(
                        af[ms], bf[ns], acc[ms][ns], 0, 0, 0);
        }
    }

    __syncthreads();   // A-stage region is now dead; reuse sm as a_lds[384][68]

    // ---- epilogue phase 1: a = f2bf(acc + bias) -> a_lds[channel][pixel] ----
    // C/D belief: col(N)=lane&15, row(M)=quad*4+reg; 4 consecutive m -> b64 write
#pragma unroll
    for (int ms = 0; ms < 4; ++ms) {
#pragma unroll
        for (int ns = 0; ns < 6; ++ns) {
            int n = n0 + ns * 16 + l16;
            float bv = bias[n];
            s16x4 pk;
#pragma unroll
            for (int r4 = 0; r4 < 4; ++r4)
                pk[r4] = (short)f2bf(acc[ms][ns][r4] + bv);
            *(s16x4*)&sm[n * 68 + ms * 16 + quad * 4] = pk;
        }
    }
    __syncthreads();

    // ---- epilogue phase A: 8-wide batched affine + coalesced permuted out-half ----
    // lane = pixel m (2 rows x 32 w); wave owns channels [wave*48, wave*48+48).
    {
        const int m = lane;
        const int h = h0 + (m >> 5);
        const int w = m & 31;
        const int cbase = wave * 48;
        const float* xb = x + ((size_t)b * 96 + (T == 4 ? 48 : 0)) * 4096
                          + (2 * h) * 64 + 2 * w;   // base at (cin=0 local, row 2h, col 2w)
#pragma unroll
        for (int i0 = 0; i0 < 48; i0 += 8) {
            int cin0 = (cbase + i0) >> 2;           // local cin of j=0..3
            // hoisted x loads: rows 2h (dy=0) and 2h+1 (dy=1) for cin0 and cin0+1
            float2 xa0 = *(const float2*)(xb + (size_t)cin0 * 4096);
            float2 xa1 = *(const float2*)(xb + (size_t)cin0 * 4096 + 64);
            float2 xb0 = *(const float2*)(xb + (size_t)(cin0 + 1) * 4096);
            float2 xb1 = *(const float2*)(xb + (size_t)(cin0 + 1) * 4096 + 64);
            float xs[8] = {xa0.x, xa0.y, xa1.x, xa1.y, xb0.x, xb0.y, xb1.x, xb1.y};
            // hoisted LDS reads
            float as_[8], ao_[8];
#pragma unroll
            for (int j = 0; j < 8; ++j) {
                int c = cbase + i0 + j;
                as_[j] = bf2f(sm[c * 68 + m]);
                ao_[j] = bf2f(sm[(c + 192) * 68 + m]);
            }
            // compute + store (fast affine chain)
#pragma unroll
            for (int j = 0; j < 8; ++j) {
                int c = cbase + i0 + j;
                float y = xs[j] * aff_fast(as_[j]) + ao_[j];
                int cg = (T == 4) ? (192 + c) : c;
                int o = inv[cg];
                if (T == 4) {
                    u16 yb = f2bf(y);
                    sm[c * 68 + m] = yb;   // stash y2' (row c owned by this wave)
                    out[(((size_t)b * 384 + o) * 32 + h) * 32 + w] =
                        bf2f(yb) * scale[cg] + offs[cg];
                } else {
                    out[(((size_t)b * 384 + o) * 32 + h) * 32 + w] =
                        y * scale[cg] + offs[cg];
                }
            }
        }
    }

    // ---- epilogue phase B (T=4 only): emit y2' in SWIZZLED global layout ----
    if (T == 4) {
        __syncthreads();
        for (int it = 0; it < 6; ++it) {
            int v = it * 256 + tid;        // 1536 = 64 pixels x 24 c-octets
            int m2 = v / 24;
            int c8 = v - m2 * 24;          // granule g = c8
            int c0 = c8 * 8;
            int h2 = h0 + (m2 >> 5);
            int w2 = m2 & 31;
            s16x8 yv;
#pragma unroll
            for (int j = 0; j < 8; ++j)
                yv[j] = (short)sm[(c0 + j) * 68 + m2];
            size_t off = ((size_t)b * 32 + h2) * 6144 + w2 * 192 + ((c8 ^ (w2 & 7)) << 3);
            *(s16x8*)&y2out[off] = yv;
        }
    }
}

extern "C" void kernel_launch(void* const* d_in, const int* in_sizes, int n_in,
                              void* d_out, int out_size, void* d_ws, size_t ws_size,
                              hipStream_t stream)
{
    const float* x        = (const float*)d_in[0];
    const float* w_hi     = (const float*)d_in[1];
    const float* b_hi     = (const float*)d_in[2];
    const float* w_lo     = (const float*)d_in[3];
    const float* b_lo     = (const float*)d_in[4];
    const float* act_norm = (const float*)d_in[5];
    const float* act_off  = (const float*)d_in[6];
    const float* perm_w   = (const float*)d_in[7];
    float* out = (float*)d_out;
    char* ws = (char*)d_ws;

    int*   fwd   = (int*)(ws + WS_FWD);
    int*   inv   = (int*)(ws + WS_INV);
    float* scale = (float*)(ws + WS_SCALE);
    float* offs  = (float*)(ws + WS_OFFS);
    u16*   whi   = (u16*)(ws + WS_WHI);
    u16*   wlo   = (u16*)(ws + WS_WLO);
    u16*   y2    = (u16*)(ws + WS_Y2);

    k_setup<<<864, 256, 0, stream>>>(perm_w, act_norm, act_off, w_hi, w_lo,
                                     fwd, inv, scale, offs, whi, wlo);
    f_gemm<4><<<512, 256, 0, stream>>>(y2, whi, b_hi, x, inv, scale, offs, y2, out);
    f_gemm<9><<<512, 256, 0, stream>>>(y2, wlo, b_lo, x, inv, scale, offs, y2, out);
}